// Round 7
// baseline (249.339 us; speedup 1.0000x reference)
//
#include <hip/hip_runtime.h>
#include <hip/hip_bf16.h>
#include <stdint.h>

#define N_TOK 16384
#define HDIM  1024
#define NE    8

#define BM 128
#define BN 128
#define BK 64
#define NKT (HDIM / BK)            // 16
#define NT_N (HDIM / BN)           // 8
#define MAXTILES (N_TOK / BM + NE) // 136 worst-case row-tiles (136 % 8 == 0)
#define GRID_GEMM (MAXTILES * NT_N) // 1088

typedef __attribute__((ext_vector_type(8))) short          bf16x8;
typedef __attribute__((ext_vector_type(8))) unsigned short ushort8;
typedef __attribute__((ext_vector_type(4))) unsigned short ushort4v;
typedef __attribute__((ext_vector_type(4))) float          f32x4;

__device__ __forceinline__ unsigned short f2bf(float f) {
  union { float f; uint32_t u; } c; c.f = f;
  uint32_t u = c.u;
  uint32_t r = (u + 0x7fffu + ((u >> 16) & 1u)) >> 16;
  return (unsigned short)r;
}

__device__ __forceinline__ void gload_lds16(const void* g, void* l) {
  __builtin_amdgcn_global_load_lds((const __attribute__((address_space(1))) void*)g,
                                   (__attribute__((address_space(3))) void*)l, 16, 0, 0);
}

__device__ __forceinline__ void expert_range(const int* __restrict__ counts, int e,
                                             int& base, int& cnt) {
  int run = 0; base = 0; cnt = 0;
#pragma unroll
  for (int i = 0; i < NE; ++i) {
    int c = counts[i];
    if (i == e) { base = run; cnt = c; }
    run += c;
  }
}

// ---------------------------------------------------------------------------
// Gate: logits = tokens @ gate_w^T (f64 accum), top-1 argmax -> eid.
// Fuses token f32->bf16 conversion. One wave per token.
// ---------------------------------------------------------------------------
__global__ __launch_bounds__(256) void gate_kernel(
    const float* __restrict__ tokens, const float* __restrict__ gate_w,
    unsigned short* __restrict__ tokB, int* __restrict__ eid)
{
  int wid  = threadIdx.x >> 6;
  int lane = threadIdx.x & 63;
  int n    = blockIdx.x * 4 + wid;

  const float* trow = tokens + (size_t)n * HDIM;
  float4 x[4];
#pragma unroll
  for (int i = 0; i < 4; ++i)
    x[i] = *(const float4*)(trow + i * 256 + lane * 4);

  unsigned short* drow = tokB + (size_t)n * HDIM;
#pragma unroll
  for (int i = 0; i < 4; ++i) {
    ushort4v o;
    o[0] = f2bf(x[i].x); o[1] = f2bf(x[i].y);
    o[2] = f2bf(x[i].z); o[3] = f2bf(x[i].w);
    *(ushort4v*)(drow + i * 256 + lane * 4) = o;
  }

  double acc[NE];
#pragma unroll
  for (int e = 0; e < NE; ++e) {
    const float* grow = gate_w + e * HDIM;
    double a = 0.0;
#pragma unroll
    for (int i = 0; i < 4; ++i) {
      float4 g = *(const float4*)(grow + i * 256 + lane * 4);
      a += (double)x[i].x * g.x + (double)x[i].y * g.y
         + (double)x[i].z * g.z + (double)x[i].w * g.w;
    }
    acc[e] = a;
  }
#pragma unroll
  for (int off = 32; off; off >>= 1) {
#pragma unroll
    for (int e = 0; e < NE; ++e) acc[e] += __shfl_xor(acc[e], off);
  }
  if (lane == 0) {
    int best = 0; double bv = acc[0];
#pragma unroll
    for (int e = 1; e < NE; ++e) if (acc[e] > bv) { bv = acc[e]; best = e; }
    eid[n] = best;
  }
}

// ---------------------------------------------------------------------------
// Rank: LDS histogram per 256-token block; 8 global atomics per block.
// ---------------------------------------------------------------------------
__global__ __launch_bounds__(256) void rank_kernel(
    const int* __restrict__ eid, int* __restrict__ rank, int* __restrict__ counts)
{
  __shared__ int h[NE];
  __shared__ int bbase[NE];
  int t = threadIdx.x;
  int n = blockIdx.x * 256 + t;
  if (t < NE) h[t] = 0;
  __syncthreads();
  int e = eid[n];
  int r = atomicAdd(&h[e], 1);
  __syncthreads();
  if (t < NE) bbase[t] = atomicAdd(&counts[t], h[t]);
  __syncthreads();
  rank[n] = bbase[e] + r;
}

// perm: prefix over counts inline, scatter token index into expert-sorted order
__global__ __launch_bounds__(256) void perm_kernel(
    const int* __restrict__ counts, const int* __restrict__ eid,
    const int* __restrict__ rank, int* __restrict__ topos)
{
  __shared__ int off[NE];
  int t = threadIdx.x;
  if (t == 0) {
    int run = 0;
#pragma unroll
    for (int e = 0; e < NE; ++e) { off[e] = run; run += counts[e]; }
  }
  __syncthreads();
  int n = blockIdx.x * 256 + t;
  topos[off[eid[n]] + rank[n]] = n;
}

// tilemap: enumerate active (e, mt) row-tiles -> compact grid for the GEMMs.
// tmeta[0] = n_tiles; tmeta[1+i] = (mt<<3)|e
__global__ void tilemap_kernel(const int* __restrict__ counts, int* __restrict__ tmeta) {
  if (threadIdx.x == 0) {
    int idx = 0;
    for (int e = 0; e < NE; ++e) {
      int ntile = (counts[e] + BM - 1) / BM;
      for (int mt = 0; mt < ntile; ++mt) tmeta[1 + idx++] = (mt << 3) | e;
    }
    tmeta[0] = idx;
  }
}

// ---------------------------------------------------------------------------
// Grouped GEMM, round-5 proven structure: 128x128 tile, BK=64, 4 waves (2x2),
// single 32KB LDS buffer, 2 syncthreads per K-tile, compiler-scheduled waits.
// NEW: B operand staged from f32 weights directly (global f32 -> reg -> f2bf
// -> swizzled ds_write) -- eliminates the separate weight-conversion pass.
// A staged via global_load_lds with pre-swizzled source (0 conflicts, r4/r5).
// XCD-chunked block swizzle (FETCH 141->36 MB, r5 verified).
// ---------------------------------------------------------------------------
#define GEMM_PREAMBLE()                                                        \
  int bid = blockIdx.x;                                                        \
  int logical = (bid & 7) * (GRID_GEMM / 8) + (bid >> 3);                      \
  int tile = logical >> 3;                                                     \
  int nt   = logical & 7;                                                      \
  if (tile >= tmeta[0]) return;                                                \
  int ent = tmeta[1 + tile];                                                   \
  int e = ent & 7, mt = ent >> 3;                                              \
  int base, cnt;                                                               \
  expert_range(counts, e, base, cnt);                                          \
  __shared__ unsigned short Alds[BM * BK];                                     \
  __shared__ unsigned short Blds[BN * BK];                                     \
  int t    = threadIdx.x;                                                      \
  int kc   = t & 7;            /* A: 16B chunk within row */                   \
  int rowi = t >> 3;           /* A: 0..31 */                                  \
  int sch  = kc ^ (rowi & 7);  /* A: inverse-swizzled source chunk */          \
  int browl = t >> 1;          /* B: LDS row 0..127 */                         \
  int bh    = t & 1;           /* B: half-row 0/1 */                           \
  int bphys[4];                                                                \
  _Pragma("unroll")                                                            \
  for (int cc = 0; cc < 4; ++cc) bphys[cc] = (bh * 4 + cc) ^ (browl & 7);      \
  int lane = t & 63, wid = t >> 6;                                             \
  int wr = wid >> 1, wc = wid & 1;                                             \
  f32x4 acc[4][4] = {};                                                        \
  int arow0 = wr * 64 + (lane & 15);                                           \
  int brow0 = wc * 64 + (lane & 15);                                           \
  int hi    = lane >> 4;       /* 0..3 */                                      \
  int xo    = lane & 7;        /* read-side XOR */

#define GEMM_STAGE(kt)                                                         \
  _Pragma("unroll")                                                            \
  for (int r = 0; r < 4; ++r)                                                  \
    gload_lds16(aptr[r] + (size_t)(kt) * BK, Alds + t * 8 + 2048 * r);         \
  {                                                                            \
    const float* bs = bsrcF + (size_t)(kt) * BK;                               \
    _Pragma("unroll")                                                          \
    for (int cc = 0; cc < 4; ++cc) {                                           \
      float4 fa = *(const float4*)(bs + cc * 8);                               \
      float4 fb = *(const float4*)(bs + cc * 8 + 4);                           \
      ushort8 o;                                                               \
      o[0] = f2bf(fa.x); o[1] = f2bf(fa.y); o[2] = f2bf(fa.z); o[3] = f2bf(fa.w); \
      o[4] = f2bf(fb.x); o[5] = f2bf(fb.y); o[6] = f2bf(fb.z); o[7] = f2bf(fb.w); \
      *(ushort8*)(Blds + browl * BK + bphys[cc] * 8) = o;                      \
    }                                                                          \
  }

#define GEMM_COMPUTE()                                                         \
  _Pragma("unroll")                                                            \
  for (int ks = 0; ks < 2; ++ks) {                                             \
    int ch = ((ks * 4 + hi) ^ xo) * 8;                                         \
    bf16x8 af[4], bv[4];                                                       \
    _Pragma("unroll")                                                          \
    for (int m = 0; m < 4; ++m)                                                \
      af[m] = *(const bf16x8*)(Alds + (arow0 + m * 16) * BK + ch);             \
    _Pragma("unroll")                                                          \
    for (int n2 = 0; n2 < 4; ++n2)                                             \
      bv[n2] = *(const bf16x8*)(Blds + (brow0 + n2 * 16) * BK + ch);           \
    _Pragma("unroll")                                                          \
    for (int m = 0; m < 4; ++m)                                                \
      _Pragma("unroll")                                                        \
      for (int n2 = 0; n2 < 4; ++n2)                                           \
        acc[m][n2] = __builtin_amdgcn_mfma_f32_16x16x32_bf16(                  \
            af[m], bv[n2], acc[m][n2], 0, 0, 0);                               \
  }

#define GEMM_MAINLOOP()                                                        \
  for (int kt = 0; kt < NKT; ++kt) {                                           \
    __syncthreads();                                                           \
    GEMM_STAGE(kt);                                                            \
    __syncthreads();                                                           \
    GEMM_COMPUTE();                                                            \
  }

__global__ __launch_bounds__(256) void gemm1_kernel(
    const unsigned short* __restrict__ tokB,  // [N][H] bf16 token order
    const float* __restrict__ w1f,            // [E][H][H] f32
    const float* __restrict__ b1,             // [E][H]
    const int* __restrict__ counts,
    const int* __restrict__ tmeta,
    const int* __restrict__ topos,
    unsigned short* __restrict__ Hbuf)        // [N][H] compacted bf16
{
  GEMM_PREAMBLE()
  const unsigned short* aptr[4];
#pragma unroll
  for (int r = 0; r < 4; ++r) {
    int pos = base + mt * BM + rowi + 32 * r;
    if (pos > N_TOK - 1) pos = N_TOK - 1;
    aptr[r] = tokB + (size_t)topos[pos] * HDIM + sch * 8;
  }
  const float* bsrcF =
      w1f + ((size_t)e << 20) + (size_t)(nt * BN + browl) * HDIM + bh * 32;
  GEMM_MAINLOOP()

  int crow0 = wr * 64 + (lane >> 4) * 4;
  int ccol0 = wc * 64 + (lane & 15);
  float bias[4];
#pragma unroll
  for (int n2 = 0; n2 < 4; ++n2)
    bias[n2] = b1[e * HDIM + nt * BN + ccol0 + n2 * 16];
#pragma unroll
  for (int m = 0; m < 4; ++m) {
#pragma unroll
    for (int j = 0; j < 4; ++j) {
      int row = crow0 + m * 16 + j;
      if (mt * BM + row < cnt) {
        size_t orow = (size_t)(base + mt * BM + row) * HDIM + nt * BN;
#pragma unroll
        for (int n2 = 0; n2 < 4; ++n2) {
          float v = acc[m][n2][j] + bias[n2];
          v = v > 0.f ? v : 0.f;
          Hbuf[orow + ccol0 + n2 * 16] = f2bf(v);
        }
      }
    }
  }
}

__global__ __launch_bounds__(256) void gemm2_kernel(
    const unsigned short* __restrict__ Hbuf,  // [N][H] compacted bf16
    const float* __restrict__ w2f,            // [E][H][H] f32
    const float* __restrict__ b2,             // [E][H]
    const int* __restrict__ counts,
    const int* __restrict__ tmeta,
    const int* __restrict__ topos,
    float* __restrict__ out)                  // [N][H] token order
{
  GEMM_PREAMBLE()
  const unsigned short* aptr[4];
#pragma unroll
  for (int r = 0; r < 4; ++r) {
    int pos = base + mt * BM + rowi + 32 * r;
    if (pos > N_TOK - 1) pos = N_TOK - 1;
    aptr[r] = Hbuf + (size_t)pos * HDIM + sch * 8;
  }
  const float* bsrcF =
      w2f + ((size_t)e << 20) + (size_t)(nt * BN + browl) * HDIM + bh * 32;
  GEMM_MAINLOOP()

  int crow0 = wr * 64 + (lane >> 4) * 4;
  int ccol0 = wc * 64 + (lane & 15);
  float bias[4];
#pragma unroll
  for (int n2 = 0; n2 < 4; ++n2)
    bias[n2] = b2[e * HDIM + nt * BN + ccol0 + n2 * 16];
#pragma unroll
  for (int m = 0; m < 4; ++m) {
#pragma unroll
    for (int j = 0; j < 4; ++j) {
      int row = crow0 + m * 16 + j;
      if (mt * BM + row < cnt) {
        int tok = topos[base + mt * BM + row];
        size_t orow = (size_t)tok * HDIM + nt * BN;
#pragma unroll
        for (int n2 = 0; n2 < 4; ++n2)
          out[orow + ccol0 + n2 * 16] = acc[m][n2][j] + bias[n2];
      }
    }
  }
}

extern "C" void kernel_launch(void* const* d_in, const int* in_sizes, int n_in,
                              void* d_out, int out_size, void* d_ws, size_t ws_size,
                              hipStream_t stream) {
  (void)in_sizes; (void)n_in; (void)out_size; (void)ws_size;
  const float* tokens = (const float*)d_in[0];
  const float* gate_w = (const float*)d_in[1];
  const float* w1     = (const float*)d_in[2];
  const float* b1     = (const float*)d_in[3];
  const float* w2     = (const float*)d_in[4];
  const float* b2     = (const float*)d_in[5];
  float* out          = (float*)d_out;

  char* ws = (char*)d_ws;
  size_t o = 0;
  int* counts = (int*)(ws + o); o += 256;
  int* tmeta  = (int*)(ws + o); o += 1024;
  int* eid    = (int*)(ws + o); o += (size_t)N_TOK * 4;
  int* rank   = (int*)(ws + o); o += (size_t)N_TOK * 4;
  int* topos  = (int*)(ws + o); o += (size_t)N_TOK * 4;
  unsigned short* tokB = (unsigned short*)(ws + o); o += (size_t)N_TOK * HDIM * 2;
  unsigned short* Hbuf = (unsigned short*)(ws + o); o += (size_t)N_TOK * HDIM * 2;

  hipMemsetAsync(counts, 0, 64, stream);
  gate_kernel<<<N_TOK / 4, 256, 0, stream>>>(tokens, gate_w, tokB, eid);
  rank_kernel<<<N_TOK / 256, 256, 0, stream>>>(eid, rank, counts);
  perm_kernel<<<N_TOK / 256, 256, 0, stream>>>(counts, eid, rank, topos);
  tilemap_kernel<<<1, 64, 0, stream>>>(counts, tmeta);
  gemm1_kernel<<<GRID_GEMM, 256, 0, stream>>>(tokB, w1, b1, counts, tmeta, topos, Hbuf);
  gemm2_kernel<<<GRID_GEMM, 256, 0, stream>>>(Hbuf, w2, b2, counts, tmeta, topos, out);
}

// Round 8
// 233.615 us; speedup vs baseline: 1.0673x; 1.0673x over previous
//
#include <hip/hip_runtime.h>
#include <hip/hip_bf16.h>
#include <stdint.h>

#define N_TOK 16384
#define HDIM  1024
#define NE    8

#define BM 128
#define BN 128
#define BK 64
#define NKT (HDIM / BK)            // 16
#define NT_N (HDIM / BN)           // 8
#define MAXTILES (N_TOK / BM + NE) // 136 worst-case row-tiles (136 % 8 == 0)
#define GRID_GEMM (MAXTILES * NT_N) // 1088

typedef __attribute__((ext_vector_type(8))) short          bf16x8;
typedef __attribute__((ext_vector_type(8))) unsigned short ushort8;
typedef __attribute__((ext_vector_type(4))) unsigned short ushort4v;
typedef __attribute__((ext_vector_type(4))) float          f32x4;

__device__ __forceinline__ unsigned short f2bf(float f) {
  union { float f; uint32_t u; } c; c.f = f;
  uint32_t u = c.u;
  uint32_t r = (u + 0x7fffu + ((u >> 16) & 1u)) >> 16;
  return (unsigned short)r;
}

__device__ __forceinline__ void gload_lds16(const void* g, void* l) {
  __builtin_amdgcn_global_load_lds((const __attribute__((address_space(1))) void*)g,
                                   (__attribute__((address_space(3))) void*)l, 16, 0, 0);
}

__device__ __forceinline__ void expert_range(const int* __restrict__ counts, int e,
                                             int& base, int& cnt) {
  int run = 0; base = 0; cnt = 0;
#pragma unroll
  for (int i = 0; i < NE; ++i) {
    int c = counts[i];
    if (i == e) { base = run; cnt = c; }
    run += c;
  }
}

// ---------------------------------------------------------------------------
// Gate + weight-cvt fused: per block, (a) 4 waves gate 4 tokens (f64 logits,
// argmax -> eid; token f32->bf16 -> tokB), (b) block converts a 4096-elem
// slice of w1/w2 to bf16. Two independent BW-bound streams in one launch.
// ---------------------------------------------------------------------------
__global__ __launch_bounds__(256) void gate_kernel(
    const float* __restrict__ tokens, const float* __restrict__ gate_w,
    const float* __restrict__ w1f, const float* __restrict__ w2f,
    unsigned short* __restrict__ tokB, unsigned short* __restrict__ w1B,
    unsigned short* __restrict__ w2B, int* __restrict__ eid)
{
  int wid  = threadIdx.x >> 6;
  int lane = threadIdx.x & 63;
  int n    = blockIdx.x * 4 + wid;

  const float* trow = tokens + (size_t)n * HDIM;
  float4 x[4];
#pragma unroll
  for (int i = 0; i < 4; ++i)
    x[i] = *(const float4*)(trow + i * 256 + lane * 4);

  unsigned short* drow = tokB + (size_t)n * HDIM;
#pragma unroll
  for (int i = 0; i < 4; ++i) {
    ushort4v o;
    o[0] = f2bf(x[i].x); o[1] = f2bf(x[i].y);
    o[2] = f2bf(x[i].z); o[3] = f2bf(x[i].w);
    *(ushort4v*)(drow + i * 256 + lane * 4) = o;
  }

  double acc[NE];
#pragma unroll
  for (int e = 0; e < NE; ++e) {
    const float* grow = gate_w + e * HDIM;
    double a = 0.0;
#pragma unroll
    for (int i = 0; i < 4; ++i) {
      float4 g = *(const float4*)(grow + i * 256 + lane * 4);
      a += (double)x[i].x * g.x + (double)x[i].y * g.y
         + (double)x[i].z * g.z + (double)x[i].w * g.w;
    }
    acc[e] = a;
  }
#pragma unroll
  for (int off = 32; off; off >>= 1) {
#pragma unroll
    for (int e = 0; e < NE; ++e) acc[e] += __shfl_xor(acc[e], off);
  }
  if (lane == 0) {
    int best = 0; double bv = acc[0];
#pragma unroll
    for (int e = 1; e < NE; ++e) if (acc[e] > bv) { bv = acc[e]; best = e; }
    eid[n] = best;
  }

  // weight conversion slice: blocks 0..2047 -> w1, 2048..4095 -> w2.
  // 4096 elems/block, 16 elems/thread.
  {
    int b = blockIdx.x;
    const float* src = (b < 2048) ? w1f : w2f;
    unsigned short* dst = (b < 2048) ? w1B : w2B;
    size_t i0 = ((size_t)(b & 2047) * 4096) + (size_t)threadIdx.x * 16;
#pragma unroll
    for (int h = 0; h < 2; ++h) {
      float4 fa = *(const float4*)(src + i0 + h * 8);
      float4 fb = *(const float4*)(src + i0 + h * 8 + 4);
      ushort8 o;
      o[0] = f2bf(fa.x); o[1] = f2bf(fa.y); o[2] = f2bf(fa.z); o[3] = f2bf(fa.w);
      o[4] = f2bf(fb.x); o[5] = f2bf(fb.y); o[6] = f2bf(fb.z); o[7] = f2bf(fb.w);
      *(ushort8*)(dst + i0 + h * 8) = o;
    }
  }
}

// ---------------------------------------------------------------------------
// Rank: LDS histogram per 256-token block; 8 global atomics per block.
// ---------------------------------------------------------------------------
__global__ __launch_bounds__(256) void rank_kernel(
    const int* __restrict__ eid, int* __restrict__ rank, int* __restrict__ counts)
{
  __shared__ int h[NE];
  __shared__ int bbase[NE];
  int t = threadIdx.x;
  int n = blockIdx.x * 256 + t;
  if (t < NE) h[t] = 0;
  __syncthreads();
  int e = eid[n];
  int r = atomicAdd(&h[e], 1);
  __syncthreads();
  if (t < NE) bbase[t] = atomicAdd(&counts[t], h[t]);
  __syncthreads();
  rank[n] = bbase[e] + r;
}

// perm_compact: one wave per token. dst = off[e]+rank; writes topos and
// copies the bf16 token row into compacted order tokC (linear A for GEMM1).
__global__ __launch_bounds__(256) void perm_compact_kernel(
    const int* __restrict__ counts, const int* __restrict__ eid,
    const int* __restrict__ rank, const unsigned short* __restrict__ tokB,
    unsigned short* __restrict__ tokC, int* __restrict__ topos)
{
  __shared__ int off[NE];
  int t = threadIdx.x;
  if (t < NE) {
    int run = 0;
    for (int i = 0; i < t; ++i) run += counts[i];
    off[t] = run;
  }
  __syncthreads();
  int wid = t >> 6, lane = t & 63;
  int n = blockIdx.x * 4 + wid;
  int dst = off[eid[n]] + rank[n];
  if (lane == 0) topos[dst] = n;
  const ushort8* s = (const ushort8*)(tokB + (size_t)n * HDIM);
  ushort8* d = (ushort8*)(tokC + (size_t)dst * HDIM);
  d[lane]      = s[lane];
  d[lane + 64] = s[lane + 64];
}

// tilemap: enumerate active (e, mt) row-tiles -> compact grid for the GEMMs.
__global__ void tilemap_kernel(const int* __restrict__ counts, int* __restrict__ tmeta) {
  if (threadIdx.x == 0) {
    int idx = 0;
    for (int e = 0; e < NE; ++e) {
      int ntile = (counts[e] + BM - 1) / BM;
      for (int mt = 0; mt < ntile; ++mt) tmeta[1 + idx++] = (mt << 3) | e;
    }
    tmeta[0] = idx;
  }
}

// ---------------------------------------------------------------------------
// Grouped GEMM: 128x128 tile, BK=64, 4 waves (2x2), DOUBLE-buffered LDS
// (64 KB) with T3-minimum 2-phase prefetch: STAGE(kt+1) issued BEFORE
// COMPUTE(kt); plain __syncthreads (implicit vmcnt(0)+lgkmcnt(0) drain keeps
// compiler scheduling intact -- r3/r6 showed hand-placed waits regress).
// Both-sides chunk-XOR LDS swizzle (0 conflicts, r4/r5 verified).
// XCD-chunked block swizzle (FETCH 141->36 MB, r5 verified).
// ---------------------------------------------------------------------------
#define GEMM_PREAMBLE()                                                        \
  int bid = blockIdx.x;                                                        \
  int logical = (bid & 7) * (GRID_GEMM / 8) + (bid >> 3);                      \
  int tile = logical >> 3;                                                     \
  int nt   = logical & 7;                                                      \
  if (tile >= tmeta[0]) return;                                                \
  int ent = tmeta[1 + tile];                                                   \
  int e = ent & 7, mt = ent >> 3;                                              \
  int base, cnt;                                                               \
  expert_range(counts, e, base, cnt);                                          \
  __shared__ unsigned short Alds[2][BM * BK];                                  \
  __shared__ unsigned short Blds[2][BN * BK];                                  \
  int t    = threadIdx.x;                                                      \
  int kc   = t & 7;            /* 16B chunk within row */                      \
  int rowi = t >> 3;           /* 0..31 */                                     \
  int sch  = kc ^ (rowi & 7);  /* inverse-swizzled source chunk */             \
  int lane = t & 63, wid = t >> 6;                                             \
  int wr = wid >> 1, wc = wid & 1;                                             \
  f32x4 acc[4][4] = {};                                                        \
  int arow0 = wr * 64 + (lane & 15);                                           \
  int brow0 = wc * 64 + (lane & 15);                                           \
  int hi    = lane >> 4;       /* 0..3 */                                      \
  int xo    = lane & 7;        /* read-side XOR */

#define GEMM_STAGE(buf, kt)                                                    \
  _Pragma("unroll")                                                            \
  for (int r = 0; r < 4; ++r) {                                                \
    gload_lds16(aptr[r] + (size_t)(kt) * BK, &Alds[buf][t * 8 + 2048 * r]);    \
    gload_lds16(bsrc + (size_t)(kt) * BK + (size_t)(32 * r) * HDIM,            \
                &Blds[buf][t * 8 + 2048 * r]);                                 \
  }

#define GEMM_COMPUTE(buf)                                                      \
  _Pragma("unroll")                                                            \
  for (int ks = 0; ks < 2; ++ks) {                                             \
    int ch = ((ks * 4 + hi) ^ xo) * 8;                                         \
    bf16x8 af[4], bv[4];                                                       \
    _Pragma("unroll")                                                          \
    for (int m = 0; m < 4; ++m)                                                \
      af[m] = *(const bf16x8*)(&Alds[buf][(arow0 + m * 16) * BK + ch]);        \
    _Pragma("unroll")                                                          \
    for (int n2 = 0; n2 < 4; ++n2)                                             \
      bv[n2] = *(const bf16x8*)(&Blds[buf][(brow0 + n2 * 16) * BK + ch]);      \
    _Pragma("unroll")                                                          \
    for (int m = 0; m < 4; ++m)                                                \
      _Pragma("unroll")                                                        \
      for (int n2 = 0; n2 < 4; ++n2)                                           \
        acc[m][n2] = __builtin_amdgcn_mfma_f32_16x16x32_bf16(                  \
            af[m], bv[n2], acc[m][n2], 0, 0, 0);                               \
  }

#define GEMM_MAINLOOP()                                                        \
  GEMM_STAGE(0, 0);                                                            \
  for (int kt = 0; kt < NKT; ++kt) {                                           \
    __syncthreads();                                                           \
    if (kt < NKT - 1) { GEMM_STAGE((kt + 1) & 1, kt + 1); }                    \
    GEMM_COMPUTE(kt & 1);                                                      \
  }

__global__ __launch_bounds__(256) void gemm1_kernel(
    const unsigned short* __restrict__ tokC,  // [N][H] compacted bf16 tokens
    const unsigned short* __restrict__ w1B,   // [E][H][H] bf16
    const float* __restrict__ b1,             // [E][H]
    const int* __restrict__ counts,
    const int* __restrict__ tmeta,
    unsigned short* __restrict__ Hbuf)        // [N][H] compacted bf16
{
  GEMM_PREAMBLE()
  const unsigned short* aptr[4];
#pragma unroll
  for (int r = 0; r < 4; ++r) {
    int pos = base + mt * BM + rowi + 32 * r;
    if (pos > N_TOK - 1) pos = N_TOK - 1;
    aptr[r] = tokC + (size_t)pos * HDIM + sch * 8;
  }
  const unsigned short* bsrc =
      w1B + ((size_t)e << 20) + (size_t)(nt * BN + rowi) * HDIM + sch * 8;
  GEMM_MAINLOOP()

  int crow0 = wr * 64 + (lane >> 4) * 4;
  int ccol0 = wc * 64 + (lane & 15);
  float bias[4];
#pragma unroll
  for (int n2 = 0; n2 < 4; ++n2)
    bias[n2] = b1[e * HDIM + nt * BN + ccol0 + n2 * 16];
#pragma unroll
  for (int m = 0; m < 4; ++m) {
#pragma unroll
    for (int j = 0; j < 4; ++j) {
      int row = crow0 + m * 16 + j;
      if (mt * BM + row < cnt) {
        size_t orow = (size_t)(base + mt * BM + row) * HDIM + nt * BN;
#pragma unroll
        for (int n2 = 0; n2 < 4; ++n2) {
          float v = acc[m][n2][j] + bias[n2];
          v = v > 0.f ? v : 0.f;
          Hbuf[orow + ccol0 + n2 * 16] = f2bf(v);
        }
      }
    }
  }
}

__global__ __launch_bounds__(256) void gemm2_kernel(
    const unsigned short* __restrict__ Hbuf,  // [N][H] compacted bf16
    const unsigned short* __restrict__ w2B,   // [E][H][H] bf16
    const float* __restrict__ b2,             // [E][H]
    const int* __restrict__ counts,
    const int* __restrict__ tmeta,
    const int* __restrict__ topos,
    float* __restrict__ out)                  // [N][H] token order
{
  GEMM_PREAMBLE()
  const unsigned short* aptr[4];
#pragma unroll
  for (int r = 0; r < 4; ++r) {
    int pos = base + mt * BM + rowi + 32 * r;
    if (pos > N_TOK - 1) pos = N_TOK - 1;
    aptr[r] = Hbuf + (size_t)pos * HDIM + sch * 8;
  }
  const unsigned short* bsrc =
      w2B + ((size_t)e << 20) + (size_t)(nt * BN + rowi) * HDIM + sch * 8;
  GEMM_MAINLOOP()

  int crow0 = wr * 64 + (lane >> 4) * 4;
  int ccol0 = wc * 64 + (lane & 15);
  float bias[4];
#pragma unroll
  for (int n2 = 0; n2 < 4; ++n2)
    bias[n2] = b2[e * HDIM + nt * BN + ccol0 + n2 * 16];
#pragma unroll
  for (int m = 0; m < 4; ++m) {
#pragma unroll
    for (int j = 0; j < 4; ++j) {
      int row = crow0 + m * 16 + j;
      if (mt * BM + row < cnt) {
        int tok = topos[base + mt * BM + row];
        size_t orow = (size_t)tok * HDIM + nt * BN;
#pragma unroll
        for (int n2 = 0; n2 < 4; ++n2)
          out[orow + ccol0 + n2 * 16] = acc[m][n2][j] + bias[n2];
      }
    }
  }
}

extern "C" void kernel_launch(void* const* d_in, const int* in_sizes, int n_in,
                              void* d_out, int out_size, void* d_ws, size_t ws_size,
                              hipStream_t stream) {
  (void)in_sizes; (void)n_in; (void)out_size; (void)ws_size;
  const float* tokens = (const float*)d_in[0];
  const float* gate_w = (const float*)d_in[1];
  const float* w1     = (const float*)d_in[2];
  const float* b1     = (const float*)d_in[3];
  const float* w2     = (const float*)d_in[4];
  const float* b2     = (const float*)d_in[5];
  float* out          = (float*)d_out;

  char* ws = (char*)d_ws;
  size_t o = 0;
  int* counts = (int*)(ws + o); o += 256;
  int* tmeta  = (int*)(ws + o); o += 1024;
  int* eid    = (int*)(ws + o); o += (size_t)N_TOK * 4;
  int* rank   = (int*)(ws + o); o += (size_t)N_TOK * 4;
  int* topos  = (int*)(ws + o); o += (size_t)N_TOK * 4;
  unsigned short* tokB = (unsigned short*)(ws + o); o += (size_t)N_TOK * HDIM * 2;
  unsigned short* tokC = (unsigned short*)(ws + o); o += (size_t)N_TOK * HDIM * 2;
  unsigned short* w1B  = (unsigned short*)(ws + o); o += (size_t)NE * HDIM * HDIM * 2;
  unsigned short* w2B  = (unsigned short*)(ws + o); o += (size_t)NE * HDIM * HDIM * 2;
  unsigned short* Hbuf = (unsigned short*)(ws + o); o += (size_t)N_TOK * HDIM * 2;

  hipMemsetAsync(counts, 0, 64, stream);
  gate_kernel<<<N_TOK / 4, 256, 0, stream>>>(tokens, gate_w, w1, w2,
                                             tokB, w1B, w2B, eid);
  rank_kernel<<<N_TOK / 256, 256, 0, stream>>>(eid, rank, counts);
  perm_compact_kernel<<<N_TOK / 4, 256, 0, stream>>>(counts, eid, rank, tokB, tokC, topos);
  tilemap_kernel<<<1, 64, 0, stream>>>(counts, tmeta);
  gemm1_kernel<<<GRID_GEMM, 256, 0, stream>>>(tokC, w1B, b1, counts, tmeta, Hbuf);
  gemm2_kernel<<<GRID_GEMM, 256, 0, stream>>>(Hbuf, w2B, b2, counts, tmeta, topos, out);
}

// Round 10
// 210.184 us; speedup vs baseline: 1.1863x; 1.1115x over previous
//
#include <hip/hip_runtime.h>
#include <hip/hip_bf16.h>
#include <stdint.h>

#define N_TOK 16384
#define HDIM  1024
#define NE    8

#define BM 256
#define BN 256
#define BK 64
#define NKT (HDIM / BK)              // 16
#define NT_N (HDIM / BN)             // 4
#define MAXTILES (N_TOK / BM + NE)   // 72 worst-case row-tiles
#define GRID_GEMM (MAXTILES * NT_N)  // 288, % 8 == 0

typedef __attribute__((ext_vector_type(8))) short          bf16x8;
typedef __attribute__((ext_vector_type(8))) unsigned short ushort8;
typedef __attribute__((ext_vector_type(4))) unsigned short ushort4v;
typedef __attribute__((ext_vector_type(4))) float          f32x4;

__device__ __forceinline__ unsigned short f2bf(float f) {
  union { float f; uint32_t u; } c; c.f = f;
  uint32_t u = c.u;
  uint32_t r = (u + 0x7fffu + ((u >> 16) & 1u)) >> 16;
  return (unsigned short)r;
}

__device__ __forceinline__ void gload_lds16(const void* g, void* l) {
  __builtin_amdgcn_global_load_lds((const __attribute__((address_space(1))) void*)g,
                                   (__attribute__((address_space(3))) void*)l, 16, 0, 0);
}

__device__ __forceinline__ void expert_range(const int* __restrict__ counts, int e,
                                             int& base, int& cnt) {
  int run = 0; base = 0; cnt = 0;
#pragma unroll
  for (int i = 0; i < NE; ++i) {
    int c = counts[i];
    if (i == e) { base = run; cnt = c; }
    run += c;
  }
}

// ---------------------------------------------------------------------------
// Gate + weight-cvt fused (r8-verified): 4 waves gate 4 tokens (f64 logits,
// argmax; token f32->bf16); block also converts a 4096-elem weight slice.
// ---------------------------------------------------------------------------
__global__ __launch_bounds__(256) void gate_kernel(
    const float* __restrict__ tokens, const float* __restrict__ gate_w,
    const float* __restrict__ w1f, const float* __restrict__ w2f,
    unsigned short* __restrict__ tokB, unsigned short* __restrict__ w1B,
    unsigned short* __restrict__ w2B, int* __restrict__ eid)
{
  int wid  = threadIdx.x >> 6;
  int lane = threadIdx.x & 63;
  int n    = blockIdx.x * 4 + wid;

  const float* trow = tokens + (size_t)n * HDIM;
  float4 x[4];
#pragma unroll
  for (int i = 0; i < 4; ++i)
    x[i] = *(const float4*)(trow + i * 256 + lane * 4);

  unsigned short* drow = tokB + (size_t)n * HDIM;
#pragma unroll
  for (int i = 0; i < 4; ++i) {
    ushort4v o;
    o[0] = f2bf(x[i].x); o[1] = f2bf(x[i].y);
    o[2] = f2bf(x[i].z); o[3] = f2bf(x[i].w);
    *(ushort4v*)(drow + i * 256 + lane * 4) = o;
  }

  double acc[NE];
#pragma unroll
  for (int e = 0; e < NE; ++e) {
    const float* grow = gate_w + e * HDIM;
    double a = 0.0;
#pragma unroll
    for (int i = 0; i < 4; ++i) {
      float4 g = *(const float4*)(grow + i * 256 + lane * 4);
      a += (double)x[i].x * g.x + (double)x[i].y * g.y
         + (double)x[i].z * g.z + (double)x[i].w * g.w;
    }
    acc[e] = a;
  }
#pragma unroll
  for (int off = 32; off; off >>= 1) {
#pragma unroll
    for (int e = 0; e < NE; ++e) acc[e] += __shfl_xor(acc[e], off);
  }
  if (lane == 0) {
    int best = 0; double bv = acc[0];
#pragma unroll
    for (int e = 1; e < NE; ++e) if (acc[e] > bv) { bv = acc[e]; best = e; }
    eid[n] = best;
  }

  {
    int b = blockIdx.x;
    const float* src = (b < 2048) ? w1f : w2f;
    unsigned short* dst = (b < 2048) ? w1B : w2B;
    size_t i0 = ((size_t)(b & 2047) * 4096) + (size_t)threadIdx.x * 16;
#pragma unroll
    for (int h = 0; h < 2; ++h) {
      float4 fa = *(const float4*)(src + i0 + h * 8);
      float4 fb = *(const float4*)(src + i0 + h * 8 + 4);
      ushort8 o;
      o[0] = f2bf(fa.x); o[1] = f2bf(fa.y); o[2] = f2bf(fa.z); o[3] = f2bf(fa.w);
      o[4] = f2bf(fb.x); o[5] = f2bf(fb.y); o[6] = f2bf(fb.z); o[7] = f2bf(fb.w);
      *(ushort8*)(dst + i0 + h * 8) = o;
    }
  }
}

// ---------------------------------------------------------------------------
__global__ __launch_bounds__(256) void rank_kernel(
    const int* __restrict__ eid, int* __restrict__ rank, int* __restrict__ counts)
{
  __shared__ int h[NE];
  __shared__ int bbase[NE];
  int t = threadIdx.x;
  int n = blockIdx.x * 256 + t;
  if (t < NE) h[t] = 0;
  __syncthreads();
  int e = eid[n];
  int r = atomicAdd(&h[e], 1);
  __syncthreads();
  if (t < NE) bbase[t] = atomicAdd(&counts[t], h[t]);
  __syncthreads();
  rank[n] = bbase[e] + r;
}

__global__ __launch_bounds__(256) void perm_kernel(
    const int* __restrict__ counts, const int* __restrict__ eid,
    const int* __restrict__ rank, int* __restrict__ topos)
{
  __shared__ int off[NE];
  int t = threadIdx.x;
  if (t == 0) {
    int run = 0;
#pragma unroll
    for (int e = 0; e < NE; ++e) { off[e] = run; run += counts[e]; }
  }
  __syncthreads();
  int n = blockIdx.x * 256 + t;
  topos[off[eid[n]] + rank[n]] = n;
}

__global__ void tilemap_kernel(const int* __restrict__ counts, int* __restrict__ tmeta) {
  if (threadIdx.x == 0) {
    int idx = 0;
    for (int e = 0; e < NE; ++e) {
      int ntile = (counts[e] + BM - 1) / BM;
      for (int mt = 0; mt < ntile; ++mt) tmeta[1 + idx++] = (mt << 3) | e;
    }
    tmeta[0] = idx;
  }
}

// ---------------------------------------------------------------------------
// Grouped GEMM, T3-minimum 2-phase at 256x256: 8 waves (2Mx4N), BK=64,
// double-buffered LDS (128 KB, 1 block/CU). Loop body per K-tile:
//   STAGE(next buf, kt+1)   // 8 async gload_lds issued first
//   COMPUTE(cur buf)        // 24 ds_read_b128 + 64 MFMA per wave
//   __syncthreads()         // implicit vmcnt(0)+lgkmcnt(0) BEFORE barrier ->
//                           // all waves' stages retired when anyone crosses
// (race-free by construction: reads of a buffer are MFMA-consumed before the
// barrier that precedes its overwrite; r9's race was vmcnt-after-barrier.)
// Both-sides chunk-XOR swizzle (0 conflicts, r4/r5). XCD-chunked grid.
// ---------------------------------------------------------------------------
#define GEMM_PREAMBLE()                                                        \
  int bid = blockIdx.x;                                                        \
  int logical = (bid & 7) * (GRID_GEMM / 8) + (bid >> 3);                      \
  int tile = logical >> 2;                                                     \
  int nt   = logical & 3;                                                      \
  if (tile >= tmeta[0]) return;                                                \
  int ent = tmeta[1 + tile];                                                   \
  int e = ent & 7, mt = ent >> 3;                                              \
  int base, cnt;                                                               \
  expert_range(counts, e, base, cnt);                                          \
  __shared__ unsigned short LA[2][BM * BK];                                    \
  __shared__ unsigned short LB[2][BN * BK];                                    \
  int t    = threadIdx.x;      /* 0..511 */                                    \
  int kc   = t & 7;            /* 16B chunk within 64-elem row */              \
  int rowi = t >> 3;           /* 0..63 */                                     \
  int sch  = kc ^ (rowi & 7);  /* inverse-swizzled source chunk */             \
  int lane = t & 63, wid = t >> 6;                                             \
  int wr = wid >> 2, wc = wid & 3;                                             \
  int l15 = lane & 15, hi = lane >> 4, xo = lane & 7;                          \
  f32x4 acc[8][4] = {};

#define GEMM_STAGE(buf, kt)                                                    \
  _Pragma("unroll")                                                            \
  for (int r = 0; r < 4; ++r) {                                                \
    gload_lds16(aptr[r] + (size_t)(kt) * BK, &LA[buf][t * 8 + 4096 * r]);      \
    gload_lds16(bptr[r] + (size_t)(kt) * BK, &LB[buf][t * 8 + 4096 * r]);      \
  }

#define GEMM_COMPUTE(buf)                                                      \
  _Pragma("unroll")                                                            \
  for (int ks = 0; ks < 2; ++ks) {                                             \
    int ch = ((ks * 4 + hi) ^ xo) * 8;                                         \
    bf16x8 af[8], bv[4];                                                       \
    _Pragma("unroll")                                                          \
    for (int m = 0; m < 8; ++m)                                                \
      af[m] = *(const bf16x8*)(&LA[buf][(wr * 128 + m * 16 + l15) * BK + ch]); \
    _Pragma("unroll")                                                          \
    for (int n2 = 0; n2 < 4; ++n2)                                             \
      bv[n2] = *(const bf16x8*)(&LB[buf][(wc * 64 + n2 * 16 + l15) * BK + ch]);\
    _Pragma("unroll")                                                          \
    for (int m = 0; m < 8; ++m)                                                \
      _Pragma("unroll")                                                        \
      for (int n2 = 0; n2 < 4; ++n2)                                           \
        acc[m][n2] = __builtin_amdgcn_mfma_f32_16x16x32_bf16(                  \
            af[m], bv[n2], acc[m][n2], 0, 0, 0);                               \
  }

#define GEMM_MAINLOOP()                                                        \
  GEMM_STAGE(0, 0);                                                            \
  __syncthreads();                                                             \
  for (int kt = 0; kt < NKT; ++kt) {                                           \
    if (kt < NKT - 1) { GEMM_STAGE((kt + 1) & 1, kt + 1); }                    \
    GEMM_COMPUTE(kt & 1);                                                      \
    __syncthreads();                                                           \
  }

__global__ __launch_bounds__(512, 1) void gemm1_kernel(
    const unsigned short* __restrict__ tokB,  // [N][H] bf16 token order
    const unsigned short* __restrict__ w1B,   // [E][H][H] bf16
    const float* __restrict__ b1,             // [E][H]
    const int* __restrict__ counts,
    const int* __restrict__ tmeta,
    const int* __restrict__ topos,
    unsigned short* __restrict__ Hbuf)        // [N][H] compacted bf16
{
  GEMM_PREAMBLE()
  const unsigned short* aptr[4];
  const unsigned short* bptr[4];
#pragma unroll
  for (int r = 0; r < 4; ++r) {
    int pos = base + mt * BM + rowi + 64 * r;
    if (pos > N_TOK - 1) pos = N_TOK - 1;
    aptr[r] = tokB + (size_t)topos[pos] * HDIM + sch * 8;
    bptr[r] = w1B + ((size_t)e << 20) + (size_t)(nt * BN + rowi + 64 * r) * HDIM + sch * 8;
  }
  GEMM_MAINLOOP()

  int ccol0 = wc * 64 + l15;
  float bias[4];
#pragma unroll
  for (int n2 = 0; n2 < 4; ++n2)
    bias[n2] = b1[e * HDIM + nt * BN + ccol0 + n2 * 16];
#pragma unroll
  for (int m = 0; m < 8; ++m) {
#pragma unroll
    for (int j = 0; j < 4; ++j) {
      int row = wr * 128 + m * 16 + hi * 4 + j;
      if (mt * BM + row < cnt) {
        size_t orow = (size_t)(base + mt * BM + row) * HDIM + nt * BN;
#pragma unroll
        for (int n2 = 0; n2 < 4; ++n2) {
          float v = acc[m][n2][j] + bias[n2];
          v = v > 0.f ? v : 0.f;
          Hbuf[orow + ccol0 + n2 * 16] = f2bf(v);
        }
      }
    }
  }
}

__global__ __launch_bounds__(512, 1) void gemm2_kernel(
    const unsigned short* __restrict__ Hbuf,  // [N][H] compacted bf16
    const unsigned short* __restrict__ w2B,   // [E][H][H] bf16
    const float* __restrict__ b2,             // [E][H]
    const int* __restrict__ counts,
    const int* __restrict__ tmeta,
    const int* __restrict__ topos,
    float* __restrict__ out)                  // [N][H] token order
{
  GEMM_PREAMBLE()
  const unsigned short* aptr[4];
  const unsigned short* bptr[4];
#pragma unroll
  for (int r = 0; r < 4; ++r) {
    int pos = base + mt * BM + rowi + 64 * r;
    if (pos > N_TOK - 1) pos = N_TOK - 1;
    aptr[r] = Hbuf + (size_t)pos * HDIM + sch * 8;
    bptr[r] = w2B + ((size_t)e << 20) + (size_t)(nt * BN + rowi + 64 * r) * HDIM + sch * 8;
  }
  GEMM_MAINLOOP()

  int ccol0 = wc * 64 + l15;
  float bias[4];
#pragma unroll
  for (int n2 = 0; n2 < 4; ++n2)
    bias[n2] = b2[e * HDIM + nt * BN + ccol0 + n2 * 16];
#pragma unroll
  for (int m = 0; m < 8; ++m) {
#pragma unroll
    for (int j = 0; j < 4; ++j) {
      int row = wr * 128 + m * 16 + hi * 4 + j;
      if (mt * BM + row < cnt) {
        int tok = topos[base + mt * BM + row];
        size_t orow = (size_t)tok * HDIM + nt * BN;
#pragma unroll
        for (int n2 = 0; n2 < 4; ++n2)
          out[orow + ccol0 + n2 * 16] = acc[m][n2][j] + bias[n2];
      }
    }
  }
}

extern "C" void kernel_launch(void* const* d_in, const int* in_sizes, int n_in,
                              void* d_out, int out_size, void* d_ws, size_t ws_size,
                              hipStream_t stream) {
  (void)in_sizes; (void)n_in; (void)out_size; (void)ws_size;
  const float* tokens = (const float*)d_in[0];
  const float* gate_w = (const float*)d_in[1];
  const float* w1     = (const float*)d_in[2];
  const float* b1     = (const float*)d_in[3];
  const float* w2     = (const float*)d_in[4];
  const float* b2     = (const float*)d_in[5];
  float* out          = (float*)d_out;

  char* ws = (char*)d_ws;
  size_t o = 0;
  int* counts = (int*)(ws + o); o += 256;
  int* tmeta  = (int*)(ws + o); o += 1024;
  int* eid    = (int*)(ws + o); o += (size_t)N_TOK * 4;
  int* rank   = (int*)(ws + o); o += (size_t)N_TOK * 4;
  int* topos  = (int*)(ws + o); o += (size_t)N_TOK * 4;
  unsigned short* tokB = (unsigned short*)(ws + o); o += (size_t)N_TOK * HDIM * 2;
  unsigned short* w1B  = (unsigned short*)(ws + o); o += (size_t)NE * HDIM * HDIM * 2;
  unsigned short* w2B  = (unsigned short*)(ws + o); o += (size_t)NE * HDIM * HDIM * 2;
  unsigned short* Hbuf = (unsigned short*)(ws + o); o += (size_t)N_TOK * HDIM * 2;

  hipMemsetAsync(counts, 0, 64, stream);
  gate_kernel<<<N_TOK / 4, 256, 0, stream>>>(tokens, gate_w, w1, w2,
                                             tokB, w1B, w2B, eid);
  rank_kernel<<<N_TOK / 256, 256, 0, stream>>>(eid, rank, counts);
  perm_kernel<<<N_TOK / 256, 256, 0, stream>>>(counts, eid, rank, topos);
  tilemap_kernel<<<1, 64, 0, stream>>>(counts, tmeta);
  gemm1_kernel<<<GRID_GEMM, 512, 0, stream>>>(tokB, w1B, b1, counts, tmeta, topos, Hbuf);
  gemm2_kernel<<<GRID_GEMM, 512, 0, stream>>>(Hbuf, w2B, b2, counts, tmeta, topos, out);
}

// Round 11
// 170.576 us; speedup vs baseline: 1.4617x; 1.2322x over previous
//
#include <hip/hip_runtime.h>
#include <hip/hip_bf16.h>
#include <stdint.h>

#define N_TOK 16384
#define HDIM  1024
#define NE    8

#define BM 128
#define BN 128
#define BK 64
#define NKT (HDIM / BK)            // 16
#define NT_N (HDIM / BN)           // 8
#define MAXTILES (N_TOK / BM + NE) // 136 worst-case row-tiles (136 % 8 == 0)
#define GRID_GEMM (MAXTILES * NT_N) // 1088

typedef __attribute__((ext_vector_type(8))) short          bf16x8;
typedef __attribute__((ext_vector_type(8))) unsigned short ushort8;
typedef __attribute__((ext_vector_type(4))) unsigned short ushort4v;
typedef __attribute__((ext_vector_type(4))) float          f32x4;

__device__ __forceinline__ unsigned short f2bf(float f) {
  union { float f; uint32_t u; } c; c.f = f;
  uint32_t u = c.u;
  uint32_t r = (u + 0x7fffu + ((u >> 16) & 1u)) >> 16;
  return (unsigned short)r;
}

__device__ __forceinline__ void gload_lds16(const void* g, void* l) {
  __builtin_amdgcn_global_load_lds((const __attribute__((address_space(1))) void*)g,
                                   (__attribute__((address_space(3))) void*)l, 16, 0, 0);
}

__device__ __forceinline__ void expert_range(const int* __restrict__ counts, int e,
                                             int& base, int& cnt) {
  int run = 0; base = 0; cnt = 0;
#pragma unroll
  for (int i = 0; i < NE; ++i) {
    int c = counts[i];
    if (i == e) { base = run; cnt = c; }
    run += c;
  }
}

// ---------------------------------------------------------------------------
// Gate + weight-cvt fused (r8-verified): 4 waves gate 4 tokens (f64 logits,
// argmax -> eid; token f32->bf16 -> tokB); the block also converts a
// 4096-element slice of w1/w2 to bf16. One ~200 MB BW-bound stream.
// ---------------------------------------------------------------------------
__global__ __launch_bounds__(256) void gate_kernel(
    const float* __restrict__ tokens, const float* __restrict__ gate_w,
    const float* __restrict__ w1f, const float* __restrict__ w2f,
    unsigned short* __restrict__ tokB, unsigned short* __restrict__ w1B,
    unsigned short* __restrict__ w2B, int* __restrict__ eid)
{
  int wid  = threadIdx.x >> 6;
  int lane = threadIdx.x & 63;
  int n    = blockIdx.x * 4 + wid;

  const float* trow = tokens + (size_t)n * HDIM;
  float4 x[4];
#pragma unroll
  for (int i = 0; i < 4; ++i)
    x[i] = *(const float4*)(trow + i * 256 + lane * 4);

  unsigned short* drow = tokB + (size_t)n * HDIM;
#pragma unroll
  for (int i = 0; i < 4; ++i) {
    ushort4v o;
    o[0] = f2bf(x[i].x); o[1] = f2bf(x[i].y);
    o[2] = f2bf(x[i].z); o[3] = f2bf(x[i].w);
    *(ushort4v*)(drow + i * 256 + lane * 4) = o;
  }

  double acc[NE];
#pragma unroll
  for (int e = 0; e < NE; ++e) {
    const float* grow = gate_w + e * HDIM;
    double a = 0.0;
#pragma unroll
    for (int i = 0; i < 4; ++i) {
      float4 g = *(const float4*)(grow + i * 256 + lane * 4);
      a += (double)x[i].x * g.x + (double)x[i].y * g.y
         + (double)x[i].z * g.z + (double)x[i].w * g.w;
    }
    acc[e] = a;
  }
#pragma unroll
  for (int off = 32; off; off >>= 1) {
#pragma unroll
    for (int e = 0; e < NE; ++e) acc[e] += __shfl_xor(acc[e], off);
  }
  if (lane == 0) {
    int best = 0; double bv = acc[0];
#pragma unroll
    for (int e = 1; e < NE; ++e) if (acc[e] > bv) { bv = acc[e]; best = e; }
    eid[n] = best;
  }

  // weight conversion slice: blocks 0..2047 -> w1, 2048..4095 -> w2.
  {
    int b = blockIdx.x;
    const float* src = (b < 2048) ? w1f : w2f;
    unsigned short* dst = (b < 2048) ? w1B : w2B;
    size_t i0 = ((size_t)(b & 2047) * 4096) + (size_t)threadIdx.x * 16;
#pragma unroll
    for (int h = 0; h < 2; ++h) {
      float4 fa = *(const float4*)(src + i0 + h * 8);
      float4 fb = *(const float4*)(src + i0 + h * 8 + 4);
      ushort8 o;
      o[0] = f2bf(fa.x); o[1] = f2bf(fa.y); o[2] = f2bf(fa.z); o[3] = f2bf(fa.w);
      o[4] = f2bf(fb.x); o[5] = f2bf(fb.y); o[6] = f2bf(fb.z); o[7] = f2bf(fb.w);
      *(ushort8*)(dst + i0 + h * 8) = o;
    }
  }
}

// ---------------------------------------------------------------------------
// Rank: LDS histogram per 256-token block; 8 global atomics per block.
// ---------------------------------------------------------------------------
__global__ __launch_bounds__(256) void rank_kernel(
    const int* __restrict__ eid, int* __restrict__ rank, int* __restrict__ counts)
{
  __shared__ int h[NE];
  __shared__ int bbase[NE];
  int t = threadIdx.x;
  int n = blockIdx.x * 256 + t;
  if (t < NE) h[t] = 0;
  __syncthreads();
  int e = eid[n];
  int r = atomicAdd(&h[e], 1);
  __syncthreads();
  if (t < NE) bbase[t] = atomicAdd(&counts[t], h[t]);
  __syncthreads();
  rank[n] = bbase[e] + r;
}

// perm + tilemap fused: scatter token index; block 0 thread 0 also emits the
// compact active-tile list (consumed only by the NEXT kernel launch).
__global__ __launch_bounds__(256) void perm_kernel(
    const int* __restrict__ counts, const int* __restrict__ eid,
    const int* __restrict__ rank, int* __restrict__ topos,
    int* __restrict__ tmeta)
{
  __shared__ int off[NE];
  int t = threadIdx.x;
  if (t == 0) {
    int run = 0;
#pragma unroll
    for (int e = 0; e < NE; ++e) { off[e] = run; run += counts[e]; }
  }
  __syncthreads();
  int n = blockIdx.x * 256 + t;
  topos[off[eid[n]] + rank[n]] = n;
  if (blockIdx.x == 0 && t == 0) {
    int idx = 0;
    for (int e = 0; e < NE; ++e) {
      int ntile = (counts[e] + BM - 1) / BM;
      for (int mt = 0; mt < ntile; ++mt) tmeta[1 + idx++] = (mt << 3) | e;
    }
    tmeta[0] = idx;
  }
}

// ---------------------------------------------------------------------------
// Grouped GEMM, r5-verified m97 structure: 128x128 tile, BK=64, 4 waves (2x2),
// single 32KB LDS buffer, 2 syncthreads per K-tile, compiler-scheduled waits.
// Both-sides chunk-XOR LDS swizzle (0 conflicts). XCD-chunked block swizzle
// (17 consecutive tiles ~ one expert per XCD; FETCH 141->36 MB).
// ---------------------------------------------------------------------------
#define GEMM_PREAMBLE()                                                        \
  int bid = blockIdx.x;                                                        \
  int logical = (bid & 7) * (GRID_GEMM / 8) + (bid >> 3);                      \
  int tile = logical >> 3;                                                     \
  int nt   = logical & 7;                                                      \
  if (tile >= tmeta[0]) return;                                                \
  int ent = tmeta[1 + tile];                                                   \
  int e = ent & 7, mt = ent >> 3;                                              \
  int base, cnt;                                                               \
  expert_range(counts, e, base, cnt);                                          \
  __shared__ unsigned short Alds[BM * BK];                                     \
  __shared__ unsigned short Blds[BN * BK];                                     \
  int t    = threadIdx.x;                                                      \
  int kc   = t & 7;            /* 16B chunk within row */                      \
  int rowi = t >> 3;           /* 0..31 */                                     \
  int sch  = kc ^ (rowi & 7);  /* inverse-swizzled source chunk */             \
  int lane = t & 63, wid = t >> 6;                                             \
  int wr = wid >> 1, wc = wid & 1;                                             \
  f32x4 acc[4][4] = {};                                                        \
  int arow0 = wr * 64 + (lane & 15);                                           \
  int brow0 = wc * 64 + (lane & 15);                                           \
  int hi    = lane >> 4;       /* 0..3 */                                      \
  int xo    = lane & 7;        /* read-side XOR */

#define GEMM_STAGE(kt)                                                         \
  _Pragma("unroll")                                                            \
  for (int r = 0; r < 4; ++r) {                                                \
    gload_lds16(APTR(r, kt), Alds + t * 8 + 2048 * r);                         \
    gload_lds16(bsrc + (size_t)(kt) * BK + (size_t)(32 * r) * HDIM,            \
                Blds + t * 8 + 2048 * r);                                      \
  }

#define GEMM_COMPUTE()                                                         \
  _Pragma("unroll")                                                            \
  for (int ks = 0; ks < 2; ++ks) {                                             \
    int ch = ((ks * 4 + hi) ^ xo) * 8;                                         \
    bf16x8 af[4], bv[4];                                                       \
    _Pragma("unroll")                                                          \
    for (int m = 0; m < 4; ++m)                                                \
      af[m] = *(const bf16x8*)(Alds + (arow0 + m * 16) * BK + ch);             \
    _Pragma("unroll")                                                          \
    for (int n2 = 0; n2 < 4; ++n2)                                             \
      bv[n2] = *(const bf16x8*)(Blds + (brow0 + n2 * 16) * BK + ch);           \
    _Pragma("unroll")                                                          \
    for (int m = 0; m < 4; ++m)                                                \
      _Pragma("unroll")                                                        \
      for (int n2 = 0; n2 < 4; ++n2)                                           \
        acc[m][n2] = __builtin_amdgcn_mfma_f32_16x16x32_bf16(                  \
            af[m], bv[n2], acc[m][n2], 0, 0, 0);                               \
  }

#define GEMM_MAINLOOP()                                                        \
  for (int kt = 0; kt < NKT; ++kt) {                                           \
    __syncthreads();                                                           \
    GEMM_STAGE(kt);                                                            \
    __syncthreads();                                                           \
    GEMM_COMPUTE();                                                            \
  }

__global__ __launch_bounds__(256) void gemm1_kernel(
    const unsigned short* __restrict__ tokB,  // [N][H] token order
    const unsigned short* __restrict__ w1B,   // [E][H][H]
    const float* __restrict__ b1,             // [E][H]
    const int* __restrict__ counts,
    const int* __restrict__ tmeta,
    const int* __restrict__ topos,
    unsigned short* __restrict__ Hbuf)        // [N][H] compacted
{
  GEMM_PREAMBLE()
  int tokr[4];
#pragma unroll
  for (int r = 0; r < 4; ++r) {
    int pos = base + mt * BM + rowi + 32 * r;
    if (pos > N_TOK - 1) pos = N_TOK - 1;
    tokr[r] = topos[pos];
  }
  const unsigned short* bsrc =
      w1B + ((size_t)e << 20) + (size_t)(nt * BN + rowi) * HDIM + sch * 8;
#define APTR(r, kt) (tokB + (size_t)tokr[r] * HDIM + (kt) * BK + sch * 8)
  GEMM_MAINLOOP()
#undef APTR

  int crow0 = wr * 64 + (lane >> 4) * 4;
  int ccol0 = wc * 64 + (lane & 15);
  float bias[4];
#pragma unroll
  for (int n2 = 0; n2 < 4; ++n2)
    bias[n2] = b1[e * HDIM + nt * BN + ccol0 + n2 * 16];
#pragma unroll
  for (int m = 0; m < 4; ++m) {
#pragma unroll
    for (int j = 0; j < 4; ++j) {
      int row = crow0 + m * 16 + j;
      if (mt * BM + row < cnt) {
        size_t orow = (size_t)(base + mt * BM + row) * HDIM + nt * BN;
#pragma unroll
        for (int n2 = 0; n2 < 4; ++n2) {
          float v = acc[m][n2][j] + bias[n2];
          v = v > 0.f ? v : 0.f;
          Hbuf[orow + ccol0 + n2 * 16] = f2bf(v);
        }
      }
    }
  }
}

__global__ __launch_bounds__(256) void gemm2_kernel(
    const unsigned short* __restrict__ Hbuf,  // [N][H] compacted
    const unsigned short* __restrict__ w2B,   // [E][H][H]
    const float* __restrict__ b2,             // [E][H]
    const int* __restrict__ counts,
    const int* __restrict__ tmeta,
    const int* __restrict__ topos,
    float* __restrict__ out)                  // [N][H] token order
{
  GEMM_PREAMBLE()
  int arows[4];
#pragma unroll
  for (int r = 0; r < 4; ++r) {
    int pos = base + mt * BM + rowi + 32 * r;
    arows[r] = pos > N_TOK - 1 ? N_TOK - 1 : pos;
  }
  const unsigned short* bsrc =
      w2B + ((size_t)e << 20) + (size_t)(nt * BN + rowi) * HDIM + sch * 8;
#define APTR(r, kt) (Hbuf + (size_t)arows[r] * HDIM + (kt) * BK + sch * 8)
  GEMM_MAINLOOP()
#undef APTR

  int crow0 = wr * 64 + (lane >> 4) * 4;
  int ccol0 = wc * 64 + (lane & 15);
  float bias[4];
#pragma unroll
  for (int n2 = 0; n2 < 4; ++n2)
    bias[n2] = b2[e * HDIM + nt * BN + ccol0 + n2 * 16];
#pragma unroll
  for (int m = 0; m < 4; ++m) {
#pragma unroll
    for (int j = 0; j < 4; ++j) {
      int row = crow0 + m * 16 + j;
      if (mt * BM + row < cnt) {
        int tok = topos[base + mt * BM + row];
        size_t orow = (size_t)tok * HDIM + nt * BN;
#pragma unroll
        for (int n2 = 0; n2 < 4; ++n2)
          out[orow + ccol0 + n2 * 16] = acc[m][n2][j] + bias[n2];
      }
    }
  }
}

extern "C" void kernel_launch(void* const* d_in, const int* in_sizes, int n_in,
                              void* d_out, int out_size, void* d_ws, size_t ws_size,
                              hipStream_t stream) {
  (void)in_sizes; (void)n_in; (void)out_size; (void)ws_size;
  const float* tokens = (const float*)d_in[0];
  const float* gate_w = (const float*)d_in[1];
  const float* w1     = (const float*)d_in[2];
  const float* b1     = (const float*)d_in[3];
  const float* w2     = (const float*)d_in[4];
  const float* b2     = (const float*)d_in[5];
  float* out          = (float*)d_out;

  char* ws = (char*)d_ws;
  size_t o = 0;
  int* counts = (int*)(ws + o); o += 256;
  int* tmeta  = (int*)(ws + o); o += 1024;
  int* eid    = (int*)(ws + o); o += (size_t)N_TOK * 4;
  int* rank   = (int*)(ws + o); o += (size_t)N_TOK * 4;
  int* topos  = (int*)(ws + o); o += (size_t)N_TOK * 4;
  unsigned short* tokB = (unsigned short*)(ws + o); o += (size_t)N_TOK * HDIM * 2;
  unsigned short* w1B  = (unsigned short*)(ws + o); o += (size_t)NE * HDIM * HDIM * 2;
  unsigned short* w2B  = (unsigned short*)(ws + o); o += (size_t)NE * HDIM * HDIM * 2;
  unsigned short* Hbuf = (unsigned short*)(ws + o); o += (size_t)N_TOK * HDIM * 2;

  hipMemsetAsync(counts, 0, 64, stream);
  gate_kernel<<<N_TOK / 4, 256, 0, stream>>>(tokens, gate_w, w1, w2,
                                             tokB, w1B, w2B, eid);
  rank_kernel<<<N_TOK / 256, 256, 0, stream>>>(eid, rank, counts);
  perm_kernel<<<N_TOK / 256, 256, 0, stream>>>(counts, eid, rank, topos, tmeta);
  gemm1_kernel<<<GRID_GEMM, 256, 0, stream>>>(tokB, w1B, b1, counts, tmeta, topos, Hbuf);
  gemm2_kernel<<<GRID_GEMM, 256, 0, stream>>>(Hbuf, w2B, b2, counts, tmeta, topos, out);
}